// Round 2
// baseline (113.722 us; speedup 1.0000x reference)
//
#include <hip/hip_runtime.h>

#define N 8192
#define LOG2E 1.4426950408889634f

using f4 = __attribute__((ext_vector_type(4))) float;

#if __has_builtin(__builtin_amdgcn_exp2f)
#define EXP2(x) __builtin_amdgcn_exp2f(x)
#else
#define EXP2(x) exp2f(x)
#endif

__global__ __launch_bounds__(256) void proj_kernel(
    const float* __restrict__ q, const float* __restrict__ k, const float* __restrict__ v,
    const float* __restrict__ Wq, const float* __restrict__ bq,
    const float* __restrict__ Wk, const float* __restrict__ bk,
    const float* __restrict__ Wv, const float* __restrict__ bv,
    float* __restrict__ aq, float* __restrict__ kp, float* __restrict__ vp)
{
    const int tn = threadIdx.x & 63;
    const int tb = threadIdx.x >> 6;        // 0..3, splits the B=64 reduction
    const int n  = blockIdx.x * 64 + tn;
    float sq = 0.f, sk = 0.f, sv = 0.f;
#pragma unroll
    for (int bi = 0; bi < 16; ++bi) {
        const int b = tb * 16 + bi;
        sq = fmaf(q[b * N + n], Wq[b], sq);
        sk = fmaf(k[b * N + n], Wk[b], sk);
        sv = fmaf(v[b * N + n], Wv[b], sv);
    }
    __shared__ float red[3][4][64];
    red[0][tb][tn] = sq; red[1][tb][tn] = sk; red[2][tb][tn] = sv;
    __syncthreads();
    if (tb == 0) {
        const float fq = red[0][0][tn] + red[0][1][tn] + red[0][2][tn] + red[0][3][tn];
        const float fk = red[1][0][tn] + red[1][1][tn] + red[1][2][tn] + red[1][3][tn];
        const float fv = red[2][0][tn] + red[2][1][tn] + red[2][2][tn] + red[2][3][tn];
        // fold 1/sqrt(dk)=1/8 AND log2(e) into the q projection, so the
        // per-element exp is a single native v_exp_f32 (2^x).
        aq[n] = (fq + bq[0]) * 0.125f * LOG2E;
        kp[n] = fk + bk[0];
        vp[n] = fv + bv[0];
    }
}

__global__ __launch_bounds__(512, 2) void attn_kernel(
    const float* __restrict__ aq, const float* __restrict__ kp, const float* __restrict__ vp,
    float* __restrict__ out, float* __restrict__ attn)
{
    __shared__ float kl[N];
    __shared__ float vl[N];
    __shared__ float wmax[8], wmin[8];
    const int tid  = threadIdx.x;
    const int lane = tid & 63;
    const int wave = tid >> 6;              // 0..7

    // Stage kp, vp into LDS; track block-local min/max of kp.
    float lmax = -1e30f, lmin = 1e30f;
#pragma unroll
    for (int it = 0; it < 4; ++it) {
        const int i4 = tid + it * 512;      // float4 index, 2048 total
        const f4 kk = reinterpret_cast<const f4*>(kp)[i4];
        const f4 vv = reinterpret_cast<const f4*>(vp)[i4];
        reinterpret_cast<f4*>(kl)[i4] = kk;
        reinterpret_cast<f4*>(vl)[i4] = vv;
        lmax = fmaxf(lmax, fmaxf(fmaxf(kk[0], kk[1]), fmaxf(kk[2], kk[3])));
        lmin = fminf(lmin, fminf(fminf(kk[0], kk[1]), fminf(kk[2], kk[3])));
    }
#pragma unroll
    for (int off = 32; off; off >>= 1) {
        lmax = fmaxf(lmax, __shfl_xor(lmax, off));
        lmin = fminf(lmin, __shfl_xor(lmin, off));
    }
    if (lane == 0) { wmax[wave] = lmax; wmin[wave] = lmin; }
    __syncthreads();
    float kmax = wmax[0], kmin = wmin[0];
#pragma unroll
    for (int w = 1; w < 8; ++w) { kmax = fmaxf(kmax, wmax[w]); kmin = fminf(kmin, wmin[w]); }

    // Each wave owns 4 rows (grid = 256 blocks = 1 block/CU, single round).
    // Single pass per row: unnormalized exp values stay in 32 f4 registers;
    // after the wave reduction we scale + nontemporal-store them, so the
    // store stream of row r drains underneath the compute of row r+1.
    for (int rr = 0; rr < 4; ++rr) {
        const int r = blockIdx.x * 32 + wave * 4 + rr;
        const float a2 = aq[r];                                // scale*log2e folded in
        const float m2 = (a2 >= 0.f) ? a2 * kmax : a2 * kmin;  // true row max (log2 units)
        const float nm2 = -m2;

        f4 e[32];
        float s = 0.f, o = 0.f;
#pragma unroll
        for (int it = 0; it < 32; ++it) {
            const f4 kk = reinterpret_cast<const f4*>(kl)[lane + it * 64];
            const f4 vv = reinterpret_cast<const f4*>(vl)[lane + it * 64];
            f4 ee;
            ee[0] = EXP2(fmaf(a2, kk[0], nm2));
            ee[1] = EXP2(fmaf(a2, kk[1], nm2));
            ee[2] = EXP2(fmaf(a2, kk[2], nm2));
            ee[3] = EXP2(fmaf(a2, kk[3], nm2));
            s += (ee[0] + ee[1]) + (ee[2] + ee[3]);
            o = fmaf(ee[0], vv[0], o);
            o = fmaf(ee[1], vv[1], o);
            o = fmaf(ee[2], vv[2], o);
            o = fmaf(ee[3], vv[3], o);
            e[it] = ee;
        }
#pragma unroll
        for (int off = 32; off; off >>= 1) {
            s += __shfl_xor(s, off);
            o += __shfl_xor(o, off);
        }
        const float inv = 1.0f / s;
        if (lane == 0) out[r] = o * inv;

        f4* __restrict__ arow = reinterpret_cast<f4*>(attn + (size_t)r * N);
#pragma unroll
        for (int it = 0; it < 32; ++it) {
            f4 w = e[it];
            w[0] *= inv; w[1] *= inv; w[2] *= inv; w[3] *= inv;
            __builtin_nontemporal_store(w, &arow[lane + it * 64]);
        }
    }
}

extern "C" void kernel_launch(void* const* d_in, const int* in_sizes, int n_in,
                              void* d_out, int out_size, void* d_ws, size_t ws_size,
                              hipStream_t stream)
{
    const float* q  = (const float*)d_in[0];
    const float* k  = (const float*)d_in[1];
    const float* v  = (const float*)d_in[2];
    const float* Wq = (const float*)d_in[3];
    const float* bq = (const float*)d_in[4];
    const float* Wk = (const float*)d_in[5];
    const float* bk = (const float*)d_in[6];
    const float* Wv = (const float*)d_in[7];
    const float* bv = (const float*)d_in[8];

    float* out  = (float*)d_out;       // [N]  (first output)
    float* attn = out + N;             // [N,N] (second output)

    float* aq = (float*)d_ws;          // qp * (1/8) * log2e
    float* kp = aq + N;
    float* vp = kp + N;

    proj_kernel<<<128, 256, 0, stream>>>(q, k, v, Wq, bq, Wk, bk, Wv, bv, aq, kp, vp);
    attn_kernel<<<256, 512, 0, stream>>>(aq, kp, vp, out, attn);
}

// Round 4
// 54.004 us; speedup vs baseline: 2.1058x; 2.1058x over previous
//
#include <hip/hip_runtime.h>

#define N 8192
#define LOG2E 1.4426950408889634f

using f4 = __attribute__((ext_vector_type(4))) float;

#if __has_builtin(__builtin_amdgcn_exp2f)
#define EXP2(x) __builtin_amdgcn_exp2f(x)
#else
#define EXP2(x) exp2f(x)
#endif

__global__ __launch_bounds__(256) void proj_kernel(
    const float* __restrict__ q, const float* __restrict__ k, const float* __restrict__ v,
    const float* __restrict__ Wq, const float* __restrict__ bq,
    const float* __restrict__ Wk, const float* __restrict__ bk,
    const float* __restrict__ Wv, const float* __restrict__ bv,
    float* __restrict__ aq, float* __restrict__ kp, float* __restrict__ vp)
{
    const int tn = threadIdx.x & 63;
    const int tb = threadIdx.x >> 6;        // 0..3, splits the B=64 reduction
    const int n  = blockIdx.x * 64 + tn;
    float sq = 0.f, sk = 0.f, sv = 0.f;
#pragma unroll
    for (int bi = 0; bi < 16; ++bi) {
        const int b = tb * 16 + bi;
        sq = fmaf(q[b * N + n], Wq[b], sq);
        sk = fmaf(k[b * N + n], Wk[b], sk);
        sv = fmaf(v[b * N + n], Wv[b], sv);
    }
    __shared__ float red[3][4][64];
    red[0][tb][tn] = sq; red[1][tb][tn] = sk; red[2][tb][tn] = sv;
    __syncthreads();
    if (tb == 0) {
        const float fq = red[0][0][tn] + red[0][1][tn] + red[0][2][tn] + red[0][3][tn];
        const float fk = red[1][0][tn] + red[1][1][tn] + red[1][2][tn] + red[1][3][tn];
        const float fv = red[2][0][tn] + red[2][1][tn] + red[2][2][tn] + red[2][3][tn];
        // fold 1/sqrt(dk)=1/8 AND log2(e): per-element exp is native v_exp_f32.
        aq[n] = (fq + bq[0]) * 0.125f * LOG2E;
        kp[n] = fk + bk[0];
        vp[n] = fv + bv[0];
    }
}

// 512 blocks x 512 threads, 2 blocks/CU (64 KB LDS each), 16 rows/block,
// 2 rows/wave. Software-pipelined so stores issue continuously:
//   phase A: sum row0 (no stores)           -- 32 iters
//   phase B: store row0 || sum row1          -- 32 iters, 1 store/iter
//   phase C: store row1                      -- 32 iters, 1 store/iter
__global__ __launch_bounds__(512, 4) void attn_kernel(
    const float* __restrict__ aq, const float* __restrict__ kp, const float* __restrict__ vp,
    float* __restrict__ out, float* __restrict__ attn)
{
    __shared__ float kl[N];
    __shared__ float vl[N];
    __shared__ float wmax[8], wmin[8];
    const int tid  = threadIdx.x;
    const int lane = tid & 63;
    const int wave = tid >> 6;              // 0..7

    // Stage kp, vp into LDS; track block-local min/max of kp.
    float lmax = -1e30f, lmin = 1e30f;
#pragma unroll
    for (int it = 0; it < 4; ++it) {
        const int i4 = tid + it * 512;      // float4 index, 2048 total
        const f4 kk = reinterpret_cast<const f4*>(kp)[i4];
        const f4 vv = reinterpret_cast<const f4*>(vp)[i4];
        reinterpret_cast<f4*>(kl)[i4] = kk;
        reinterpret_cast<f4*>(vl)[i4] = vv;
        lmax = fmaxf(lmax, fmaxf(fmaxf(kk[0], kk[1]), fmaxf(kk[2], kk[3])));
        lmin = fminf(lmin, fminf(fminf(kk[0], kk[1]), fminf(kk[2], kk[3])));
    }
#pragma unroll
    for (int off = 32; off; off >>= 1) {
        lmax = fmaxf(lmax, __shfl_xor(lmax, off));
        lmin = fminf(lmin, __shfl_xor(lmin, off));
    }
    if (lane == 0) { wmax[wave] = lmax; wmin[wave] = lmin; }
    __syncthreads();
    float kmax = wmax[0], kmin = wmin[0];
#pragma unroll
    for (int w = 1; w < 8; ++w) { kmax = fmaxf(kmax, wmax[w]); kmin = fminf(kmin, wmin[w]); }

    const int r0 = blockIdx.x * 16 + wave * 2;
    const float a0 = aq[r0];
    const float a1 = aq[r0 + 1];
    const float nm0 = -((a0 >= 0.f) ? a0 * kmax : a0 * kmin);  // -rowmax, log2 units
    const float nm1 = -((a1 >= 0.f) ? a1 * kmax : a1 * kmin);

    // ---- phase A: sum row 0 ----
    float s0 = 0.f, o0 = 0.f;
#pragma unroll 8
    for (int it = 0; it < 32; ++it) {
        const f4 kk = reinterpret_cast<const f4*>(kl)[lane + it * 64];
        const f4 vv = reinterpret_cast<const f4*>(vl)[lane + it * 64];
        const float e0 = EXP2(fmaf(a0, kk[0], nm0));
        const float e1 = EXP2(fmaf(a0, kk[1], nm0));
        const float e2 = EXP2(fmaf(a0, kk[2], nm0));
        const float e3 = EXP2(fmaf(a0, kk[3], nm0));
        s0 += (e0 + e1) + (e2 + e3);
        o0 = fmaf(e0, vv[0], o0); o0 = fmaf(e1, vv[1], o0);
        o0 = fmaf(e2, vv[2], o0); o0 = fmaf(e3, vv[3], o0);
    }
#pragma unroll
    for (int off = 32; off; off >>= 1) { s0 += __shfl_xor(s0, off); o0 += __shfl_xor(o0, off); }
    if (lane == 0) out[r0] = o0 / s0;
    const float c0 = nm0 - __log2f(s0);     // normalized: attn = 2^(a0*k + c0)

    // ---- phase B: store row 0 || sum row 1 ----
    f4* __restrict__ arow0 = reinterpret_cast<f4*>(attn + (size_t)r0 * N);
    float s1 = 0.f, o1 = 0.f;
#pragma unroll 4
    for (int it = 0; it < 32; ++it) {
        const f4 kk = reinterpret_cast<const f4*>(kl)[lane + it * 64];
        const f4 vv = reinterpret_cast<const f4*>(vl)[lane + it * 64];
        f4 w;
        w[0] = EXP2(fmaf(a0, kk[0], c0));
        w[1] = EXP2(fmaf(a0, kk[1], c0));
        w[2] = EXP2(fmaf(a0, kk[2], c0));
        w[3] = EXP2(fmaf(a0, kk[3], c0));
        arow0[lane + it * 64] = w;
        const float e0 = EXP2(fmaf(a1, kk[0], nm1));
        const float e1 = EXP2(fmaf(a1, kk[1], nm1));
        const float e2 = EXP2(fmaf(a1, kk[2], nm1));
        const float e3 = EXP2(fmaf(a1, kk[3], nm1));
        s1 += (e0 + e1) + (e2 + e3);
        o1 = fmaf(e0, vv[0], o1); o1 = fmaf(e1, vv[1], o1);
        o1 = fmaf(e2, vv[2], o1); o1 = fmaf(e3, vv[3], o1);
    }
#pragma unroll
    for (int off = 32; off; off >>= 1) { s1 += __shfl_xor(s1, off); o1 += __shfl_xor(o1, off); }
    if (lane == 0) out[r0 + 1] = o1 / s1;
    const float c1 = nm1 - __log2f(s1);

    // ---- phase C: store row 1 ----
    f4* __restrict__ arow1 = reinterpret_cast<f4*>(attn + (size_t)(r0 + 1) * N);
#pragma unroll 4
    for (int it = 0; it < 32; ++it) {
        const f4 kk = reinterpret_cast<const f4*>(kl)[lane + it * 64];
        f4 w;
        w[0] = EXP2(fmaf(a1, kk[0], c1));
        w[1] = EXP2(fmaf(a1, kk[1], c1));
        w[2] = EXP2(fmaf(a1, kk[2], c1));
        w[3] = EXP2(fmaf(a1, kk[3], c1));
        arow1[lane + it * 64] = w;
    }
}

extern "C" void kernel_launch(void* const* d_in, const int* in_sizes, int n_in,
                              void* d_out, int out_size, void* d_ws, size_t ws_size,
                              hipStream_t stream)
{
    const float* q  = (const float*)d_in[0];
    const float* k  = (const float*)d_in[1];
    const float* v  = (const float*)d_in[2];
    const float* Wq = (const float*)d_in[3];
    const float* bq = (const float*)d_in[4];
    const float* Wk = (const float*)d_in[5];
    const float* bk = (const float*)d_in[6];
    const float* Wv = (const float*)d_in[7];
    const float* bv = (const float*)d_in[8];

    float* out  = (float*)d_out;       // [N]  (first output)
    float* attn = out + N;             // [N,N] (second output)

    float* aq = (float*)d_ws;          // qp * (1/8) * log2e
    float* kp = aq + N;
    float* vp = kp + N;

    proj_kernel<<<128, 256, 0, stream>>>(q, k, v, Wq, bq, Wk, bk, Wv, bv, aq, kp, vp);
    attn_kernel<<<512, 512, 0, stream>>>(aq, kp, vp, out, attn);
}